// Round 7
// baseline (113157.080 us; speedup 1.0000x reference)
//
#include <hip/hip_runtime.h>

typedef short s16x8 __attribute__((ext_vector_type(8)));
typedef unsigned short us8 __attribute__((ext_vector_type(8)));
typedef float f32x4 __attribute__((ext_vector_type(4)));

#define NWG_SCAN 64
#define TC 16   // time-chunk length

// ---------- helpers ----------
__device__ __forceinline__ ushort f2bf(float f) {
  union { float f; unsigned u; } v; v.f = f;
  unsigned u = v.u;
  u += 0x7fffu + ((u >> 16) & 1u);
  return (ushort)(u >> 16);
}
__device__ __forceinline__ float bf2f(ushort h) {
  union { unsigned u; float f; } v; v.u = ((unsigned)h) << 16; return v.f;
}
__device__ __forceinline__ float sigm(float x) { return 1.f / (1.f + __expf(-x)); }
__device__ __forceinline__ float tanh_(float x) { return 1.f - 2.f / (__expf(2.f * x) + 1.f); }

#define MFMA __builtin_amdgcn_mfma_f32_16x16x32_bf16

// device-coherent 16B load (bypass L1/L2); batch + s_waitcnt vmcnt(0) before use
__device__ __forceinline__ s16x8 ld_sc16(const ushort* p) {
  s16x8 v;
  asm volatile("global_load_dwordx4 %0, %1, off sc0 sc1" : "=v"(v) : "v"(p));
  return v;
}
// cached 16B load with identical issue/wait structure (probe baseline)
__device__ __forceinline__ s16x8 ld_c16(const ushort* p) {
  s16x8 v;
  asm volatile("global_load_dwordx4 %0, %1, off" : "=v"(v) : "v"(p));
  return v;
}
// device-coherent 2B store (write-through)
__device__ __forceinline__ void st_sc2(ushort* p, ushort x) {
  unsigned v = x;
  asm volatile("global_store_short %0, %1, off sc0 sc1" :: "v"(p), "v"(v) : "memory");
}

// ---------- transpose + split-convert: dst_{hi,lo}[n][k] = split(src[k][n]) ----------
__global__ void tr_cvt_split(const float* __restrict__ src, ushort* __restrict__ hi,
                             ushort* __restrict__ lo, int kbits, int Nsrc, int total) {
  int K1 = (1 << kbits) - 1;
  for (int i = blockIdx.x * blockDim.x + threadIdx.x; i < total; i += gridDim.x * blockDim.x) {
    int n = i >> kbits, k = i & K1;
    float v = src[(size_t)k * Nsrc + n];
    ushort h = f2bf(v);
    hi[i] = h;
    lo[i] = f2bf(v - bf2f(h));
  }
}

// ---------- split x chunk rows into hi/lo planes (chunk-row order) ----------
// chunk row ar -> global row (ar>>4)*512 + t0 + (ar&15); cols K=512
__global__ void split_x_chunk(const float* __restrict__ x, ushort* __restrict__ Xh,
                              ushort* __restrict__ Xl, int t0) {
  for (int i = blockIdx.x * blockDim.x + threadIdx.x; i < 1024 * 512;
       i += gridDim.x * blockDim.x) {
    int ar = i >> 9, k = i & 511;
    size_t grow = (size_t)(ar >> 4) * 512 + t0 + (ar & 15);
    float v = x[grow * 512 + k];
    ushort h = f2bf(v);
    Xh[i] = h;
    Xl[i] = f2bf(v - bf2f(h));
  }
}

// ---------- 3-term split GEMM from pre-split planes ----------
// C[M,N] f32 = (Ah+Al)[M,K] * (Bh+Bl)[N,K]^T ; product = AhBh + AlBh + AhBl.
// C_MODE 0: f32 contiguous chunk rows, no bias. C_MODE 1: f32 + bias, scattered rows.
template <int C_MODE>
__global__ __launch_bounds__(256) void gemm3p(
    const ushort* __restrict__ Ah, const ushort* __restrict__ Al,
    const ushort* __restrict__ Bh, const ushort* __restrict__ Bl,
    float* __restrict__ Cout, const float* __restrict__ bias,
    int M, int N, int K, int t0) {
  __shared__ __align__(16) ushort Ahs[128][72];
  __shared__ __align__(16) ushort Als[128][72];
  __shared__ __align__(16) ushort Bhs[128][72];
  __shared__ __align__(16) ushort Bls[128][72];
  const int bm = blockIdx.x, bn = blockIdx.y;
  const int tid = threadIdx.x, lane = tid & 63;
  const int w = tid >> 6;
  const int wm = (w >> 1) * 64, wn = (w & 1) * 64;
  const int lr = lane & 15;
  const int lk = (lane >> 4) * 8;
  f32x4 acc[4][4] = {};
  for (int k0 = 0; k0 < K; k0 += 64) {
#pragma unroll
    for (int i = 0; i < 4; ++i) {
      int chunk = tid + i * 256;
      int row = chunk >> 3, c = (chunk & 7) * 8;
      size_t ao = (size_t)(bm * 128 + row) * K + k0 + c;
      size_t bo = (size_t)(bn * 128 + row) * K + k0 + c;
      *(int4*)(&Ahs[row][c]) = *(const int4*)(&Ah[ao]);
      *(int4*)(&Als[row][c]) = *(const int4*)(&Al[ao]);
      *(int4*)(&Bhs[row][c]) = *(const int4*)(&Bh[bo]);
      *(int4*)(&Bls[row][c]) = *(const int4*)(&Bl[bo]);
    }
    __syncthreads();
#pragma unroll
    for (int kk = 0; kk < 64; kk += 32) {
      s16x8 ah[4], al[4], bh[4], bl[4];
#pragma unroll
      for (int i = 0; i < 4; ++i) {
        ah[i] = *(const s16x8*)(&Ahs[wm + i * 16 + lr][kk + lk]);
        al[i] = *(const s16x8*)(&Als[wm + i * 16 + lr][kk + lk]);
      }
#pragma unroll
      for (int j = 0; j < 4; ++j) {
        bh[j] = *(const s16x8*)(&Bhs[wn + j * 16 + lr][kk + lk]);
        bl[j] = *(const s16x8*)(&Bls[wn + j * 16 + lr][kk + lk]);
      }
#pragma unroll
      for (int i = 0; i < 4; ++i)
#pragma unroll
        for (int j = 0; j < 4; ++j) {
          acc[i][j] = MFMA(ah[i], bh[j], acc[i][j], 0, 0, 0);
          acc[i][j] = MFMA(al[i], bh[j], acc[i][j], 0, 0, 0);
          acc[i][j] = MFMA(ah[i], bl[j], acc[i][j], 0, 0, 0);
        }
    }
    __syncthreads();
  }
#pragma unroll
  for (int i = 0; i < 4; ++i)
#pragma unroll
    for (int j = 0; j < 4; ++j)
#pragma unroll
      for (int r = 0; r < 4; ++r) {
        int lrow = bm * 128 + wm + i * 16 + (lane >> 4) * 4 + r;
        int gcol = bn * 128 + wn + j * 16 + lr;
        float v = acc[i][j][r];
        if (C_MODE == 1) {
          size_t grow = (size_t)(lrow >> 4) * 512 + t0 + (lrow & 15);
          Cout[grow * N + gcol] = v + bias[gcol];
        } else {
          Cout[(size_t)lrow * N + gcol] = v;
        }
      }
}

// ---------- fence-free gen-poll grid barrier ----------
// cnt: monotonic arrival counter (RMW once per WG). gen: separate 128B-line word,
// written once by last arriver; others poll it read-only (no RMW-line ping-pong).
// Correctness: comm data is write-through sc0sc1, drained by vmcnt(0) before arrival.
__device__ __forceinline__ void gbar(unsigned* cnt, unsigned* gen, unsigned tgt) {
  asm volatile("s_waitcnt vmcnt(0)" ::: "memory");
  __syncthreads();
  if (threadIdx.x == 0) {
    unsigned prev = __hip_atomic_fetch_add(cnt, 1u, __ATOMIC_RELAXED, __HIP_MEMORY_SCOPE_AGENT);
    if (prev == tgt - 1u) {
      __hip_atomic_store(gen, tgt, __ATOMIC_RELAXED, __HIP_MEMORY_SCOPE_AGENT);
    } else {
      while (__hip_atomic_load(gen, __ATOMIC_RELAXED, __HIP_MEMORY_SCOPE_AGENT) < tgt)
        __builtin_amdgcn_s_sleep(1);
    }
  }
  __syncthreads();
}

// ---------- persistent GRU scan: one chunk of TC steps for one layer ----------
// Numerics identical to r4-r6 PASS. Sout now written as bf16 hi/lo planes (same values).
struct ScanArgs {
  const float* P;             // [64*TC][3072] f32 chunk (z|r|g)
  const float *bz, *br, *bg;
  const ushort *WhzrH, *WhzrL; // [2048][1024] bf16 hi/lo
  const ushort *WhgH, *WhgL;   // [1024][1024] bf16 hi/lo
  const float* h0;
  int layer, t0;
  float* h32g;                // [64][1024] f32 carry
  ushort *hbh, *hbl;          // [64][1024] bf16 hi/lo of h   (sc0sc1 comm)
  ushort *rhh, *rhl;          // [64][1024] bf16 hi/lo of r*h (sc0sc1 comm)
  ushort *Sh, *Sl;            // [64*TC][1024] bf16 hi/lo planes of h output
  float* hidout;              // [64][2][1024] f32
  unsigned *barc, *barg;      // barrier cnt / gen (separate cache lines)
  unsigned bar_base;          // launch_idx * 33 * 64
};

__global__ __launch_bounds__(256) void gru_scan(ScanArgs A) {
  __shared__ __align__(16) ushort Wz[16][1032];
  __shared__ __align__(16) ushort Wr[16][1032];
  __shared__ __align__(16) ushort Wg[16][1032];
  __shared__ __align__(16) ushort Wgl[16][1032];
  const int tid = threadIdx.x, lane = tid & 63;
  const int rb = tid >> 6;                    // rowblock 0..3
  const int wgc = blockIdx.x;                 // col slice 0..63
  const int lr = lane & 15, lkq = lane >> 4;
  const int cz = wgc * 16 + lr;               // this lane's output column
  unsigned tgt = A.bar_base;

  // stage weight hi-slices (+ Wg lo) into LDS
  {
    const ushort* srcz = A.WhzrH + (size_t)(wgc * 16) * 1024;
    const ushort* srcr = A.WhzrH + (size_t)(1024 + wgc * 16) * 1024;
    const ushort* srcg = A.WhgH + (size_t)(wgc * 16) * 1024;
    const ushort* srcgl = A.WhgL + (size_t)(wgc * 16) * 1024;
#pragma unroll
    for (int j = 0; j < 8; ++j) {
      int id = tid + j * 256;
      int row = id >> 7, ko = (id & 127) * 8;
      *(int4*)(&Wz[row][ko]) = *(const int4*)(srcz + row * 1024 + ko);
      *(int4*)(&Wr[row][ko]) = *(const int4*)(srcr + row * 1024 + ko);
      *(int4*)(&Wg[row][ko]) = *(const int4*)(srcg + row * 1024 + ko);
      *(int4*)(&Wgl[row][ko]) = *(const int4*)(srcgl + row * 1024 + ko);
    }
  }

  const int b0 = rb * 16 + lkq * 4;
  float h32[4], zv[4];
  const float bzc = A.bz[cz], brc = A.br[cz], bgc = A.bg[cz];

  if (A.t0 == 0) {
#pragma unroll
    for (int r = 0; r < 4; ++r) {
      float v = A.h0[(size_t)((b0 + r) * 2 + A.layer) * 1024 + cz];
      h32[r] = v;
      ushort hi = f2bf(v);
      st_sc2(&A.hbh[(b0 + r) * 1024 + cz], hi);
      st_sc2(&A.hbl[(b0 + r) * 1024 + cz], f2bf(v - bf2f(hi)));
    }
  } else {
#pragma unroll
    for (int r = 0; r < 4; ++r) h32[r] = A.h32g[(b0 + r) * 1024 + cz];
  }
  tgt += 64; gbar(A.barc, A.barg, tgt);   // covers LDS staging + h init visibility

  const ushort* hhp = A.hbh + (rb * 16 + lr) * 1024 + lkq * 8;
  const ushort* hlp = A.hbl + (rb * 16 + lr) * 1024 + lkq * 8;
  const ushort* rhp = A.rhh + (rb * 16 + lr) * 1024 + lkq * 8;
  const ushort* rlp = A.rhl + (rb * 16 + lr) * 1024 + lkq * 8;
  const ushort* wzl = A.WhzrL + (size_t)(wgc * 16 + lr) * 1024 + lkq * 8;
  const ushort* wrl = A.WhzrL + (size_t)(1024 + wgc * 16 + lr) * 1024 + lkq * 8;

  for (int tl = 0; tl < TC; ++tl) {
    // ---- phase A: z,r = sigmoid(P + h @ Wh{z,r}), 3-term split products ----
    f32x4 az = {}, ar4 = {};
#pragma unroll
    for (int kb = 0; kb < 4; ++kb) {
      s16x8 hhv[8], hlv[8];
#pragma unroll
      for (int e = 0; e < 8; ++e) {
        hhv[e] = ld_sc16(hhp + (kb * 8 + e) * 32);
        hlv[e] = ld_sc16(hlp + (kb * 8 + e) * 32);
      }
      asm volatile("s_waitcnt vmcnt(0)" ::: "memory");
      __builtin_amdgcn_sched_barrier(0);
#pragma unroll
      for (int e = 0; e < 8; ++e) {
        int k = kb * 8 + e;
        s16x8 wz = *(const s16x8*)(&Wz[lr][k * 32 + lkq * 8]);
        s16x8 wr = *(const s16x8*)(&Wr[lr][k * 32 + lkq * 8]);
        az = MFMA(hhv[e], wz, az, 0, 0, 0);
        az = MFMA(hlv[e], wz, az, 0, 0, 0);
        az = MFMA(hhv[e], *(const s16x8*)(wzl + k * 32), az, 0, 0, 0);
        ar4 = MFMA(hhv[e], wr, ar4, 0, 0, 0);
        ar4 = MFMA(hlv[e], wr, ar4, 0, 0, 0);
        ar4 = MFMA(hhv[e], *(const s16x8*)(wrl + k * 32), ar4, 0, 0, 0);
      }
    }
#pragma unroll
    for (int r = 0; r < 4; ++r) {
      int b = b0 + r;
      size_t prow = (size_t)(b * TC + tl) * 3072;
      zv[r] = sigm(A.P[prow + cz] + bzc + az[r]);
      float rv = sigm(A.P[prow + 1024 + cz] + brc + ar4[r]);
      float p = rv * h32[r];
      ushort ph = f2bf(p);
      st_sc2(&A.rhh[b * 1024 + cz], ph);
      st_sc2(&A.rhl[b * 1024 + cz], f2bf(p - bf2f(ph)));
    }
    tgt += 64; gbar(A.barc, A.barg, tgt);
    // ---- phase B: g = tanh(P + (r*h) @ Whg); h update ----
    f32x4 ag = {};
#pragma unroll
    for (int kb = 0; kb < 4; ++kb) {
      s16x8 rhv[8], rlv[8];
#pragma unroll
      for (int e = 0; e < 8; ++e) {
        rhv[e] = ld_sc16(rhp + (kb * 8 + e) * 32);
        rlv[e] = ld_sc16(rlp + (kb * 8 + e) * 32);
      }
      asm volatile("s_waitcnt vmcnt(0)" ::: "memory");
      __builtin_amdgcn_sched_barrier(0);
#pragma unroll
      for (int e = 0; e < 8; ++e) {
        int k = kb * 8 + e;
        s16x8 wg = *(const s16x8*)(&Wg[lr][k * 32 + lkq * 8]);
        s16x8 wl = *(const s16x8*)(&Wgl[lr][k * 32 + lkq * 8]);
        ag = MFMA(rhv[e], wg, ag, 0, 0, 0);
        ag = MFMA(rlv[e], wg, ag, 0, 0, 0);
        ag = MFMA(rhv[e], wl, ag, 0, 0, 0);
      }
    }
#pragma unroll
    for (int r = 0; r < 4; ++r) {
      int b = b0 + r;
      size_t prow = (size_t)(b * TC + tl) * 3072;
      float g = tanh_(A.P[prow + 2048 + cz] + bgc + ag[r]);
      float hn = zv[r] * h32[r] + (1.f - zv[r]) * g;
      h32[r] = hn;
      ushort hi = f2bf(hn);
      ushort lo = f2bf(hn - bf2f(hi));
      st_sc2(&A.hbh[b * 1024 + cz], hi);
      st_sc2(&A.hbl[b * 1024 + cz], lo);
      size_t so = (size_t)(b * TC + tl) * 1024 + cz;
      A.Sh[so] = hi;
      A.Sl[so] = lo;
      if (A.t0 + tl == 511) A.hidout[(size_t)(b * 2 + A.layer) * 1024 + cz] = hn;
    }
    tgt += 64; gbar(A.barc, A.barg, tgt);
  }
#pragma unroll
  for (int r = 0; r < 4; ++r) A.h32g[(b0 + r) * 1024 + cz] = h32[r];
}

// ---------- PROBE KERNELS (outputs dead; for rocprof ablation only) ----------
// probe_bar: same LDS footprint as gru_scan; 400 barriers.
// style 0 = r6 cnt-poll (poll the RMW line), style 1 = gen-poll.
__global__ __launch_bounds__(256) void probe_bar(unsigned* cnt, unsigned* gen,
                                                 int iters, int style, float* dead) {
  __shared__ ushort pad[4 * 16 * 1032];
  volatile ushort* vp = pad;
  vp[threadIdx.x] = (ushort)blockIdx.x;
  __syncthreads();
  for (int i = 1; i <= iters; ++i) {
    if (style == 0) {
      asm volatile("s_waitcnt vmcnt(0)" ::: "memory");
      __syncthreads();
      if (threadIdx.x == 0) {
        __hip_atomic_fetch_add(cnt, 1u, __ATOMIC_RELAXED, __HIP_MEMORY_SCOPE_AGENT);
        while (__hip_atomic_load(cnt, __ATOMIC_RELAXED, __HIP_MEMORY_SCOPE_AGENT) <
               (unsigned)(i * 64))
          __builtin_amdgcn_s_sleep(1);
      }
      __syncthreads();
    } else {
      gbar(cnt, gen, (unsigned)(i * 64));
    }
  }
  if (vp[0] == 60000) dead[0] = 1.f;
}

// probe_mm: phase-A replica. SC=1: sc0sc1 loads (scan's path); SC=0: cached loads.
template <int SC>
__global__ __launch_bounds__(256) void probe_mm(
    const ushort* __restrict__ WhzrH, const ushort* __restrict__ WhzrL,
    const ushort* __restrict__ WhgH, const ushort* __restrict__ WhgL,
    const ushort* __restrict__ hH, const ushort* __restrict__ hL,
    float* __restrict__ dead, int iters) {
  __shared__ __align__(16) ushort Wz[16][1032];
  __shared__ __align__(16) ushort Wr[16][1032];
  __shared__ __align__(16) ushort Wg[16][1032];
  __shared__ __align__(16) ushort Wgl[16][1032];
  const int tid = threadIdx.x, lane = tid & 63;
  const int rb = tid >> 6;
  const int wgc = blockIdx.x;
  const int lr = lane & 15, lkq = lane >> 4;
  {
    const ushort* srcz = WhzrH + (size_t)(wgc * 16) * 1024;
    const ushort* srcr = WhzrH + (size_t)(1024 + wgc * 16) * 1024;
    const ushort* srcg = WhgH + (size_t)(wgc * 16) * 1024;
    const ushort* srcgl = WhgL + (size_t)(wgc * 16) * 1024;
#pragma unroll
    for (int j = 0; j < 8; ++j) {
      int id = tid + j * 256;
      int row = id >> 7, ko = (id & 127) * 8;
      *(int4*)(&Wz[row][ko]) = *(const int4*)(srcz + row * 1024 + ko);
      *(int4*)(&Wr[row][ko]) = *(const int4*)(srcr + row * 1024 + ko);
      *(int4*)(&Wg[row][ko]) = *(const int4*)(srcg + row * 1024 + ko);
      *(int4*)(&Wgl[row][ko]) = *(const int4*)(srcgl + row * 1024 + ko);
    }
  }
  __syncthreads();
  const ushort* hhp = hH + (size_t)(rb * 16 + lr) * 1024 + lkq * 8;
  const ushort* hlp = hL + (size_t)(rb * 16 + lr) * 1024 + lkq * 8;
  const ushort* wzl = WhzrL + (size_t)(wgc * 16 + lr) * 1024 + lkq * 8;
  const ushort* wrl = WhzrL + (size_t)(1024 + wgc * 16 + lr) * 1024 + lkq * 8;
  f32x4 az = {}, ar4 = {};
  for (int it = 0; it < iters; ++it) {
#pragma unroll
    for (int kb = 0; kb < 4; ++kb) {
      s16x8 hhv[8], hlv[8];
#pragma unroll
      for (int e = 0; e < 8; ++e) {
        hhv[e] = SC ? ld_sc16(hhp + (kb * 8 + e) * 32) : ld_c16(hhp + (kb * 8 + e) * 32);
        hlv[e] = SC ? ld_sc16(hlp + (kb * 8 + e) * 32) : ld_c16(hlp + (kb * 8 + e) * 32);
      }
      asm volatile("s_waitcnt vmcnt(0)" ::: "memory");
      __builtin_amdgcn_sched_barrier(0);
#pragma unroll
      for (int e = 0; e < 8; ++e) {
        int k = kb * 8 + e;
        s16x8 wz = *(const s16x8*)(&Wz[lr][k * 32 + lkq * 8]);
        s16x8 wr = *(const s16x8*)(&Wr[lr][k * 32 + lkq * 8]);
        az = MFMA(hhv[e], wz, az, 0, 0, 0);
        az = MFMA(hlv[e], wz, az, 0, 0, 0);
        az = MFMA(hhv[e], *(const s16x8*)(wzl + k * 32), az, 0, 0, 0);
        ar4 = MFMA(hhv[e], wr, ar4, 0, 0, 0);
        ar4 = MFMA(hlv[e], wr, ar4, 0, 0, 0);
        ar4 = MFMA(hhv[e], *(const s16x8*)(wrl + k * 32), ar4, 0, 0, 0);
      }
    }
    __syncthreads();
  }
  dead[blockIdx.x * 256 + tid] = az[0] + ar4[1];
}

// ---------- workspace layout (bytes); same proven footprint as r4-r6 ----------
static constexpr size_t OFF_WXT0H   = 0;                                  // [3072][512]
static constexpr size_t OFF_WXT0L   = OFF_WXT0H + 3072ull * 512 * 2;
static constexpr size_t OFF_WHZRT0H = OFF_WXT0L + 3072ull * 512 * 2;      // [2048][1024]
static constexpr size_t OFF_WHZRT0L = OFF_WHZRT0H + 2048ull * 1024 * 2;
static constexpr size_t OFF_WHGT0H  = OFF_WHZRT0L + 2048ull * 1024 * 2;   // [1024][1024]
static constexpr size_t OFF_WHGT0L  = OFF_WHGT0H + 1024ull * 1024 * 2;
static constexpr size_t OFF_WXT1H   = OFF_WHGT0L + 1024ull * 1024 * 2;    // [3072][1024]
static constexpr size_t OFF_WXT1L   = OFF_WXT1H + 3072ull * 1024 * 2;
static constexpr size_t OFF_WHZRT1H = OFF_WXT1L + 3072ull * 1024 * 2;
static constexpr size_t OFF_WHZRT1L = OFF_WHZRT1H + 2048ull * 1024 * 2;
static constexpr size_t OFF_WHGT1H  = OFF_WHZRT1L + 2048ull * 1024 * 2;
static constexpr size_t OFF_WHGT1L  = OFF_WHGT1H + 1024ull * 1024 * 2;
static constexpr size_t OFF_WHYTH   = OFF_WHGT1L + 1024ull * 1024 * 2;    // [512][1024]
static constexpr size_t OFF_WHYTL   = OFF_WHYTH + 512ull * 1024 * 2;
static constexpr size_t OFF_PC      = OFF_WHYTL + 512ull * 1024 * 2;      // [1024][3072] f32
static constexpr size_t OFF_S0H     = OFF_PC + 1024ull * 3072 * 4;        // [1024][1024] bf16
static constexpr size_t OFF_S0L     = OFF_S0H + 1024ull * 1024 * 2;
static constexpr size_t OFF_S1H     = OFF_S0L + 1024ull * 1024 * 2;       // also Xh alias
static constexpr size_t OFF_S1L     = OFF_S1H + 1024ull * 1024 * 2;       // also Xl alias
static constexpr size_t OFF_HBH0    = OFF_S1L + 1024ull * 1024 * 2;       // [64][1024] bf16
static constexpr size_t OFF_HBL0    = OFF_HBH0 + 64ull * 1024 * 2;
static constexpr size_t OFF_HBH1    = OFF_HBL0 + 64ull * 1024 * 2;
static constexpr size_t OFF_HBL1    = OFF_HBH1 + 64ull * 1024 * 2;
static constexpr size_t OFF_H320    = OFF_HBL1 + 64ull * 1024 * 2;        // [64][1024] f32
static constexpr size_t OFF_H321    = OFF_H320 + 64ull * 1024 * 4;
static constexpr size_t OFF_RHH     = OFF_H321 + 64ull * 1024 * 4;        // [64][1024] bf16
static constexpr size_t OFF_RHL     = OFF_RHH + 64ull * 1024 * 2;
static constexpr size_t OFF_BAR     = OFF_RHL + 64ull * 1024 * 2;         // 1 KB of counters
static constexpr size_t OFF_END     = OFF_BAR + 1024;

extern "C" void kernel_launch(void* const* d_in, const int* in_sizes, int n_in,
                              void* d_out, int out_size, void* d_ws, size_t ws_size,
                              hipStream_t stream) {
  if (ws_size < OFF_END) return;  // clean fail: zeros => absmax 12.875 signature

  const float* x     = (const float*)d_in[0];
  const float* h0    = (const float*)d_in[1];
  const float* W_xz0 = (const float*)d_in[2];
  const float* W_hz0 = (const float*)d_in[3];
  const float* b_z0  = (const float*)d_in[4];
  const float* W_xr0 = (const float*)d_in[5];
  const float* W_hr0 = (const float*)d_in[6];
  const float* b_r0  = (const float*)d_in[7];
  const float* W_xg0 = (const float*)d_in[8];
  const float* W_hg0 = (const float*)d_in[9];
  const float* b_g0  = (const float*)d_in[10];
  const float* W_xz1 = (const float*)d_in[11];
  const float* W_hz1 = (const float*)d_in[12];
  const float* b_z1  = (const float*)d_in[13];
  const float* W_xr1 = (const float*)d_in[14];
  const float* W_hr1 = (const float*)d_in[15];
  const float* b_r1  = (const float*)d_in[16];
  const float* W_xg1 = (const float*)d_in[17];
  const float* W_hg1 = (const float*)d_in[18];
  const float* b_g1  = (const float*)d_in[19];
  const float* W_hy  = (const float*)d_in[20];
  const float* b_y   = (const float*)d_in[21];

  char* ws = (char*)d_ws;
  float* out_y   = (float*)d_out;                  // [64,512,512]
  float* out_hid = (float*)d_out + 16777216;       // [64,2,1024]
  unsigned* barc = (unsigned*)(ws + OFF_BAR);      // scan cnt @w0, gen @w32
                                                   // probe0 cnt @w64; probe1 cnt @w128, gen @w160

  hipMemsetAsync(barc, 0, 1024, stream);

  // weight transpose + hi/lo split: dst[n][k] = src[k][n]
#define TRS(W, OFF_H, OFF_L, kbits, Nsrc, total) \
  tr_cvt_split<<<2048, 256, 0, stream>>>(W, (ushort*)(ws + OFF_H), (ushort*)(ws + OFF_L), kbits, Nsrc, total)
  TRS(W_xz0, OFF_WXT0H,                  OFF_WXT0L,                   9, 1024, 1024 * 512);
  TRS(W_xr0, OFF_WXT0H + 1024ull*512*2,  OFF_WXT0L + 1024ull*512*2,   9, 1024, 1024 * 512);
  TRS(W_xg0, OFF_WXT0H + 2048ull*512*2,  OFF_WXT0L + 2048ull*512*2,   9, 1024, 1024 * 512);
  TRS(W_hz0, OFF_WHZRT0H,                OFF_WHZRT0L,                10, 1024, 1024 * 1024);
  TRS(W_hr0, OFF_WHZRT0H + 1024ull*1024*2, OFF_WHZRT0L + 1024ull*1024*2, 10, 1024, 1024 * 1024);
  TRS(W_hg0, OFF_WHGT0H,                 OFF_WHGT0L,                 10, 1024, 1024 * 1024);
  TRS(W_xz1, OFF_WXT1H,                  OFF_WXT1L,                  10, 1024, 1024 * 1024);
  TRS(W_xr1, OFF_WXT1H + 1024ull*1024*2, OFF_WXT1L + 1024ull*1024*2, 10, 1024, 1024 * 1024);
  TRS(W_xg1, OFF_WXT1H + 2048ull*1024*2, OFF_WXT1L + 2048ull*1024*2, 10, 1024, 1024 * 1024);
  TRS(W_hz1, OFF_WHZRT1H,                OFF_WHZRT1L,                10, 1024, 1024 * 1024);
  TRS(W_hr1, OFF_WHZRT1H + 1024ull*1024*2, OFF_WHZRT1L + 1024ull*1024*2, 10, 1024, 1024 * 1024);
  TRS(W_hg1, OFF_WHGT1H,                 OFF_WHGT1L,                 10, 1024, 1024 * 1024);
  TRS(W_hy,  OFF_WHYTH,                  OFF_WHYTL,                  10, 512,  512 * 1024);
#undef TRS

  float*  Pc  = (float*)(ws + OFF_PC);
  ushort* S0h = (ushort*)(ws + OFF_S0H);
  ushort* S0l = (ushort*)(ws + OFF_S0L);
  ushort* S1h = (ushort*)(ws + OFF_S1H);
  ushort* S1l = (ushort*)(ws + OFF_S1L);
  ushort* Xh  = S1h;  // alias: X planes live split_x -> proj0; S1 live scan1 -> outproj
  ushort* Xl  = S1l;

  for (int c = 0; c < 512 / TC; ++c) {
    int t0 = c * TC;
    // split x chunk into bf16 planes (chunk-row order)
    split_x_chunk<<<1024, 256, 0, stream>>>(x, Xh, Xl, t0);
    // layer-0 input projections: Pc = Xc @ WxT0^T   [1024,3072], K=512
    gemm3p<0><<<dim3(8, 24), 256, 0, stream>>>(
        Xh, Xl, (const ushort*)(ws + OFF_WXT0H), (const ushort*)(ws + OFF_WXT0L),
        Pc, nullptr, 1024, 3072, 512, 0);
    // layer-0 scan
    {
      ScanArgs sa;
      sa.P = Pc; sa.bz = b_z0; sa.br = b_r0; sa.bg = b_g0;
      sa.WhzrH = (const ushort*)(ws + OFF_WHZRT0H); sa.WhzrL = (const ushort*)(ws + OFF_WHZRT0L);
      sa.WhgH = (const ushort*)(ws + OFF_WHGT0H);   sa.WhgL = (const ushort*)(ws + OFF_WHGT0L);
      sa.h0 = h0; sa.layer = 0; sa.t0 = t0;
      sa.h32g = (float*)(ws + OFF_H320);
      sa.hbh = (ushort*)(ws + OFF_HBH0); sa.hbl = (ushort*)(ws + OFF_HBL0);
      sa.rhh = (ushort*)(ws + OFF_RHH);  sa.rhl = (ushort*)(ws + OFF_RHL);
      sa.Sh = S0h; sa.Sl = S0l; sa.hidout = out_hid;
      sa.barc = barc; sa.barg = barc + 32;
      sa.bar_base = (unsigned)((c * 2 + 0) * 33 * 64);
      gru_scan<<<NWG_SCAN, 256, 0, stream>>>(sa);
    }
    // layer-1 input projections: Pc = S0 @ WxT1^T  [1024,3072], K=1024
    gemm3p<0><<<dim3(8, 24), 256, 0, stream>>>(
        S0h, S0l, (const ushort*)(ws + OFF_WXT1H), (const ushort*)(ws + OFF_WXT1L),
        Pc, nullptr, 1024, 3072, 1024, 0);
    // layer-1 scan (writes S1 planes, overwriting dead X alias)
    {
      ScanArgs sa;
      sa.P = Pc; sa.bz = b_z1; sa.br = b_r1; sa.bg = b_g1;
      sa.WhzrH = (const ushort*)(ws + OFF_WHZRT1H); sa.WhzrL = (const ushort*)(ws + OFF_WHZRT1L);
      sa.WhgH = (const ushort*)(ws + OFF_WHGT1H);   sa.WhgL = (const ushort*)(ws + OFF_WHGT1L);
      sa.h0 = h0; sa.layer = 1; sa.t0 = t0;
      sa.h32g = (float*)(ws + OFF_H321);
      sa.hbh = (ushort*)(ws + OFF_HBH1); sa.hbl = (ushort*)(ws + OFF_HBL1);
      sa.rhh = (ushort*)(ws + OFF_RHH);  sa.rhl = (ushort*)(ws + OFF_RHL);
      sa.Sh = S1h; sa.Sl = S1l; sa.hidout = out_hid;
      sa.barc = barc; sa.barg = barc + 32;
      sa.bar_base = (unsigned)((c * 2 + 1) * 33 * 64);
      gru_scan<<<NWG_SCAN, 256, 0, stream>>>(sa);
    }
    // output projection: out_y rows = S1 @ WhyT^T + b_y  [1024,512], K=1024
    gemm3p<1><<<dim3(8, 4), 256, 0, stream>>>(
        S1h, S1l, (const ushort*)(ws + OFF_WHYTH), (const ushort*)(ws + OFF_WHYTL),
        out_y, b_y, 1024, 512, 1024, t0);
  }

  // ---------- probes (dead output = Pc; remove next round) ----------
  probe_bar<<<64, 256, 0, stream>>>(barc + 64, barc + 96, 400, 0, Pc);   // cnt-poll
  probe_bar<<<64, 256, 0, stream>>>(barc + 128, barc + 160, 400, 1, Pc); // gen-poll
  probe_mm<1><<<64, 256, 0, stream>>>(
      (const ushort*)(ws + OFF_WHZRT0H), (const ushort*)(ws + OFF_WHZRT0L),
      (const ushort*)(ws + OFF_WHGT0H), (const ushort*)(ws + OFF_WHGT0L),
      (const ushort*)(ws + OFF_WHGT1H), (const ushort*)(ws + OFF_WHGT1L), Pc, 2560);
  probe_mm<0><<<64, 256, 0, stream>>>(
      (const ushort*)(ws + OFF_WHZRT0H), (const ushort*)(ws + OFF_WHZRT0L),
      (const ushort*)(ws + OFF_WHGT0H), (const ushort*)(ws + OFF_WHGT0L),
      (const ushort*)(ws + OFF_WHGT1H), (const ushort*)(ws + OFF_WHGT1L), Pc, 2560);
}

// Round 8
// 23059.746 us; speedup vs baseline: 4.9071x; 4.9071x over previous
//
#include <hip/hip_runtime.h>

typedef short s16x8 __attribute__((ext_vector_type(8)));
typedef unsigned short us8 __attribute__((ext_vector_type(8)));
typedef float f32x4 __attribute__((ext_vector_type(4)));

#define TC 16   // time-chunk length

// ---------- helpers ----------
__device__ __forceinline__ ushort f2bf(float f) {
  union { float f; unsigned u; } v; v.f = f;
  unsigned u = v.u;
  u += 0x7fffu + ((u >> 16) & 1u);
  return (ushort)(u >> 16);
}
__device__ __forceinline__ float bf2f(ushort h) {
  union { unsigned u; float f; } v; v.u = ((unsigned)h) << 16; return v.f;
}
__device__ __forceinline__ float sigm(float x) { return 1.f / (1.f + __expf(-x)); }
__device__ __forceinline__ float tanh_(float x) { return 1.f - 2.f / (__expf(2.f * x) + 1.f); }

#define MFMA __builtin_amdgcn_mfma_f32_16x16x32_bf16

// device-coherent 16B load (bypass L1/L2); batch + s_waitcnt vmcnt(0) before use
__device__ __forceinline__ s16x8 ld_sc16(const ushort* p) {
  s16x8 v;
  asm volatile("global_load_dwordx4 %0, %1, off sc0 sc1" : "=v"(v) : "v"(p));
  return v;
}
// cached 16B load, same batched-wait structure (constant weight data only)
__device__ __forceinline__ s16x8 ld_c16(const ushort* p) {
  s16x8 v;
  asm volatile("global_load_dwordx4 %0, %1, off" : "=v"(v) : "v"(p));
  return v;
}
// device-coherent 2B store (write-through)
__device__ __forceinline__ void st_sc2(ushort* p, ushort x) {
  unsigned v = x;
  asm volatile("global_store_short %0, %1, off sc0 sc1" :: "v"(p), "v"(v) : "memory");
}

// ---------- transpose + split-convert: dst_{hi,lo}[n][k] = split(src[k][n]) ----------
__global__ void tr_cvt_split(const float* __restrict__ src, ushort* __restrict__ hi,
                             ushort* __restrict__ lo, int kbits, int Nsrc, int total) {
  int K1 = (1 << kbits) - 1;
  for (int i = blockIdx.x * blockDim.x + threadIdx.x; i < total; i += gridDim.x * blockDim.x) {
    int n = i >> kbits, k = i & K1;
    float v = src[(size_t)k * Nsrc + n];
    ushort h = f2bf(v);
    hi[i] = h;
    lo[i] = f2bf(v - bf2f(h));
  }
}

// ---------- split x chunk rows into hi/lo planes (chunk-row order) ----------
__global__ void split_x_chunk(const float* __restrict__ x, ushort* __restrict__ Xh,
                              ushort* __restrict__ Xl, int t0) {
  for (int i = blockIdx.x * blockDim.x + threadIdx.x; i < 1024 * 512;
       i += gridDim.x * blockDim.x) {
    int ar = i >> 9, k = i & 511;
    size_t grow = (size_t)(ar >> 4) * 512 + t0 + (ar & 15);
    float v = x[grow * 512 + k];
    ushort h = f2bf(v);
    Xh[i] = h;
    Xl[i] = f2bf(v - bf2f(h));
  }
}

// ---------- 3-term split GEMM from pre-split planes ----------
template <int C_MODE>
__global__ __launch_bounds__(256) void gemm3p(
    const ushort* __restrict__ Ah, const ushort* __restrict__ Al,
    const ushort* __restrict__ Bh, const ushort* __restrict__ Bl,
    float* __restrict__ Cout, const float* __restrict__ bias,
    int M, int N, int K, int t0) {
  __shared__ __align__(16) ushort Ahs[128][72];
  __shared__ __align__(16) ushort Als[128][72];
  __shared__ __align__(16) ushort Bhs[128][72];
  __shared__ __align__(16) ushort Bls[128][72];
  const int bm = blockIdx.x, bn = blockIdx.y;
  const int tid = threadIdx.x, lane = tid & 63;
  const int w = tid >> 6;
  const int wm = (w >> 1) * 64, wn = (w & 1) * 64;
  const int lr = lane & 15;
  const int lk = (lane >> 4) * 8;
  f32x4 acc[4][4] = {};
  for (int k0 = 0; k0 < K; k0 += 64) {
#pragma unroll
    for (int i = 0; i < 4; ++i) {
      int chunk = tid + i * 256;
      int row = chunk >> 3, c = (chunk & 7) * 8;
      size_t ao = (size_t)(bm * 128 + row) * K + k0 + c;
      size_t bo = (size_t)(bn * 128 + row) * K + k0 + c;
      *(int4*)(&Ahs[row][c]) = *(const int4*)(&Ah[ao]);
      *(int4*)(&Als[row][c]) = *(const int4*)(&Al[ao]);
      *(int4*)(&Bhs[row][c]) = *(const int4*)(&Bh[bo]);
      *(int4*)(&Bls[row][c]) = *(const int4*)(&Bl[bo]);
    }
    __syncthreads();
#pragma unroll
    for (int kk = 0; kk < 64; kk += 32) {
      s16x8 ah[4], al[4], bh[4], bl[4];
#pragma unroll
      for (int i = 0; i < 4; ++i) {
        ah[i] = *(const s16x8*)(&Ahs[wm + i * 16 + lr][kk + lk]);
        al[i] = *(const s16x8*)(&Als[wm + i * 16 + lr][kk + lk]);
      }
#pragma unroll
      for (int j = 0; j < 4; ++j) {
        bh[j] = *(const s16x8*)(&Bhs[wn + j * 16 + lr][kk + lk]);
        bl[j] = *(const s16x8*)(&Bls[wn + j * 16 + lr][kk + lk]);
      }
#pragma unroll
      for (int i = 0; i < 4; ++i)
#pragma unroll
        for (int j = 0; j < 4; ++j) {
          acc[i][j] = MFMA(ah[i], bh[j], acc[i][j], 0, 0, 0);
          acc[i][j] = MFMA(al[i], bh[j], acc[i][j], 0, 0, 0);
          acc[i][j] = MFMA(ah[i], bl[j], acc[i][j], 0, 0, 0);
        }
    }
    __syncthreads();
  }
#pragma unroll
  for (int i = 0; i < 4; ++i)
#pragma unroll
    for (int j = 0; j < 4; ++j)
#pragma unroll
      for (int r = 0; r < 4; ++r) {
        int lrow = bm * 128 + wm + i * 16 + (lane >> 4) * 4 + r;
        int gcol = bn * 128 + wn + j * 16 + lr;
        float v = acc[i][j][r];
        if (C_MODE == 1) {
          size_t grow = (size_t)(lrow >> 4) * 512 + t0 + (lrow & 15);
          Cout[grow * N + gcol] = v + bias[gcol];
        } else {
          Cout[(size_t)lrow * N + gcol] = v;
        }
      }
}

// ---------- fence-free gen-poll group barrier (proven r7) ----------
__device__ __forceinline__ void gbar(unsigned* cnt, unsigned* gen, unsigned tgt) {
  asm volatile("s_waitcnt vmcnt(0)" ::: "memory");
  __syncthreads();
  if (threadIdx.x == 0) {
    unsigned prev = __hip_atomic_fetch_add(cnt, 1u, __ATOMIC_RELAXED, __HIP_MEMORY_SCOPE_AGENT);
    if (prev == tgt - 1u) {
      __hip_atomic_store(gen, tgt, __ATOMIC_RELAXED, __HIP_MEMORY_SCOPE_AGENT);
    } else {
      while (__hip_atomic_load(gen, __ATOMIC_RELAXED, __HIP_MEMORY_SCOPE_AGENT) < tgt)
        __builtin_amdgcn_s_sleep(1);
    }
  }
  __syncthreads();
}

// ---------- persistent GRU scan: 4 independent 16-row groups x 64 col-slice WGs ----------
// Grid 256 WGs x 256 thr (1 WG/CU). Group g = blockIdx>>6 owns batch rows [16g,16g+16).
// WG owns cols [wgc*16,+16). 4 waves K-split (256 each) + LDS reduce; wave0 finalizes
// (f32 h carry in regs). Numerics: same products as r4-r7 PASS; only K-sum order differs.
struct ScanArgs {
  const float* P;              // [64*TC][3072] f32 chunk (z|r|g)
  const float *bz, *br, *bg;
  const ushort *WhzrH, *WhzrL; // [2048][1024] bf16 hi/lo
  const ushort *WhgH, *WhgL;   // [1024][1024] bf16 hi/lo
  const float* h0;
  int layer, t0;
  float* h32g;                 // [64][1024] f32 carry
  ushort *hbh, *hbl;           // [64][1024] bf16 hi/lo of h   (sc comm)
  ushort *rhh, *rhl;           // [64][1024] bf16 hi/lo of r*h (sc comm)
  ushort *Sh, *Sl;             // [64*TC][1024] bf16 hi/lo seq output
  float* hidout;               // [64][2][1024] f32
  unsigned* barc;              // per-group cnt @ +grp*32, gen @ +256+grp*32
  unsigned bar_base;           // launch_idx * 33 * 64
};

__global__ __launch_bounds__(256) void gru_scan(ScanArgs A) {
  __shared__ __align__(16) ushort Wzh[16][1032];
  __shared__ __align__(16) ushort Wzl[16][1032];
  __shared__ __align__(16) ushort Wrh[16][1032];
  __shared__ __align__(16) ushort Wrl[16][1032];
  __shared__ float red[4][64][9];
  const int tid = threadIdx.x, lane = tid & 63, w = tid >> 6;
  const int grp = blockIdx.x >> 6;
  const int wgc = blockIdx.x & 63;
  const int lr = lane & 15, lkq = lane >> 4;
  const int cz = wgc * 16 + lr;
  const int kbase = w * 256;
  unsigned tgt = A.bar_base;
  unsigned* cnt = A.barc + grp * 32;
  unsigned* gen = A.barc + 256 + grp * 32;

  // stage Wz/Wr hi+lo slices into LDS (stage-1 has zero weight VMEM)
  {
    const ushort* s0 = A.WhzrH + (size_t)(wgc * 16) * 1024;
    const ushort* s1 = A.WhzrL + (size_t)(wgc * 16) * 1024;
    const ushort* s2 = A.WhzrH + (size_t)(1024 + wgc * 16) * 1024;
    const ushort* s3 = A.WhzrL + (size_t)(1024 + wgc * 16) * 1024;
#pragma unroll
    for (int j = 0; j < 8; ++j) {
      int id = tid + j * 256;
      int row = id >> 7, ko = (id & 127) * 8;
      *(int4*)(&Wzh[row][ko]) = *(const int4*)(s0 + row * 1024 + ko);
      *(int4*)(&Wzl[row][ko]) = *(const int4*)(s1 + row * 1024 + ko);
      *(int4*)(&Wrh[row][ko]) = *(const int4*)(s2 + row * 1024 + ko);
      *(int4*)(&Wrl[row][ko]) = *(const int4*)(s3 + row * 1024 + ko);
    }
  }

  float h32[4] = {}, zv[4] = {};
  float bzc = 0.f, brc = 0.f, bgc = 0.f;
  if (w == 0) {
    bzc = A.bz[cz]; brc = A.br[cz]; bgc = A.bg[cz];
    if (A.t0 == 0) {
#pragma unroll
      for (int r = 0; r < 4; ++r) {
        int brow = grp * 16 + lkq * 4 + r;
        float v = A.h0[(size_t)(brow * 2 + A.layer) * 1024 + cz];
        h32[r] = v;
        ushort hi = f2bf(v);
        st_sc2(&A.hbh[brow * 1024 + cz], hi);
        st_sc2(&A.hbl[brow * 1024 + cz], f2bf(v - bf2f(hi)));
      }
    } else {
#pragma unroll
      for (int r = 0; r < 4; ++r)
        h32[r] = A.h32g[(grp * 16 + lkq * 4 + r) * 1024 + cz];
    }
  }
  tgt += 64; gbar(cnt, gen, tgt);   // LDS staging + h init visibility

  const ushort* hhp = A.hbh + (size_t)(grp * 16 + lr) * 1024 + kbase + lkq * 8;
  const ushort* hlp = A.hbl + (size_t)(grp * 16 + lr) * 1024 + kbase + lkq * 8;
  const ushort* rhp = A.rhh + (size_t)(grp * 16 + lr) * 1024 + kbase + lkq * 8;
  const ushort* rlp = A.rhl + (size_t)(grp * 16 + lr) * 1024 + kbase + lkq * 8;
  const ushort* wgh = A.WhgH + (size_t)(wgc * 16 + lr) * 1024 + kbase + lkq * 8;
  const ushort* wgl = A.WhgL + (size_t)(wgc * 16 + lr) * 1024 + kbase + lkq * 8;

  for (int tl = 0; tl < TC; ++tl) {
    // ---- stage 1: partial z,r over this wave's K-quarter ----
    {
      s16x8 hh[8], hl[8];
#pragma unroll
      for (int e = 0; e < 8; ++e) {
        hh[e] = ld_sc16(hhp + e * 32);
        hl[e] = ld_sc16(hlp + e * 32);
      }
      asm volatile("s_waitcnt vmcnt(0)" ::: "memory");
      __builtin_amdgcn_sched_barrier(0);
      f32x4 az = {}, ar4 = {};
#pragma unroll
      for (int ks = 0; ks < 8; ++ks) {
        int kc = kbase + ks * 32 + lkq * 8;
        s16x8 wz = *(const s16x8*)(&Wzh[lr][kc]);
        s16x8 wr = *(const s16x8*)(&Wrh[lr][kc]);
        s16x8 zl = *(const s16x8*)(&Wzl[lr][kc]);
        s16x8 rl = *(const s16x8*)(&Wrl[lr][kc]);
        az = MFMA(hh[ks], wz, az, 0, 0, 0);
        az = MFMA(hl[ks], wz, az, 0, 0, 0);
        az = MFMA(hh[ks], zl, az, 0, 0, 0);
        ar4 = MFMA(hh[ks], wr, ar4, 0, 0, 0);
        ar4 = MFMA(hl[ks], wr, ar4, 0, 0, 0);
        ar4 = MFMA(hh[ks], rl, ar4, 0, 0, 0);
      }
#pragma unroll
      for (int i = 0; i < 4; ++i) { red[w][lane][i] = az[i]; red[w][lane][4 + i] = ar4[i]; }
    }
    __syncthreads();
    if (w == 0) {
      f32x4 az, ar4;
#pragma unroll
      for (int i = 0; i < 4; ++i) {
        az[i]  = red[0][lane][i] + red[1][lane][i] + red[2][lane][i] + red[3][lane][i];
        ar4[i] = red[0][lane][4+i] + red[1][lane][4+i] + red[2][lane][4+i] + red[3][lane][4+i];
      }
#pragma unroll
      for (int r = 0; r < 4; ++r) {
        int brow = grp * 16 + lkq * 4 + r;
        size_t prow = (size_t)(brow * TC + tl) * 3072;
        zv[r] = sigm(A.P[prow + cz] + bzc + az[r]);
        float rv = sigm(A.P[prow + 1024 + cz] + brc + ar4[r]);
        float p = rv * h32[r];
        ushort ph = f2bf(p);
        st_sc2(&A.rhh[brow * 1024 + cz], ph);
        st_sc2(&A.rhl[brow * 1024 + cz], f2bf(p - bf2f(ph)));
      }
    }
    tgt += 64; gbar(cnt, gen, tgt);
    // ---- stage 2: partial g over this wave's K-quarter; wave0 updates h ----
    {
      s16x8 rh8[8], rl8[8], gh8[8], gl8[8];
#pragma unroll
      for (int e = 0; e < 8; ++e) {
        rh8[e] = ld_sc16(rhp + e * 32);
        rl8[e] = ld_sc16(rlp + e * 32);
        gh8[e] = ld_c16(wgh + e * 32);
        gl8[e] = ld_c16(wgl + e * 32);
      }
      asm volatile("s_waitcnt vmcnt(0)" ::: "memory");
      __builtin_amdgcn_sched_barrier(0);
      f32x4 ag = {};
#pragma unroll
      for (int ks = 0; ks < 8; ++ks) {
        ag = MFMA(rh8[ks], gh8[ks], ag, 0, 0, 0);
        ag = MFMA(rl8[ks], gh8[ks], ag, 0, 0, 0);
        ag = MFMA(rh8[ks], gl8[ks], ag, 0, 0, 0);
      }
#pragma unroll
      for (int i = 0; i < 4; ++i) red[w][lane][i] = ag[i];
    }
    __syncthreads();
    if (w == 0) {
      f32x4 ag;
#pragma unroll
      for (int i = 0; i < 4; ++i)
        ag[i] = red[0][lane][i] + red[1][lane][i] + red[2][lane][i] + red[3][lane][i];
#pragma unroll
      for (int r = 0; r < 4; ++r) {
        int brow = grp * 16 + lkq * 4 + r;
        size_t prow = (size_t)(brow * TC + tl) * 3072;
        float g = tanh_(A.P[prow + 2048 + cz] + bgc + ag[r]);
        float hn = zv[r] * h32[r] + (1.f - zv[r]) * g;
        h32[r] = hn;
        ushort hi = f2bf(hn);
        ushort lo = f2bf(hn - bf2f(hi));
        st_sc2(&A.hbh[brow * 1024 + cz], hi);
        st_sc2(&A.hbl[brow * 1024 + cz], lo);
        size_t so = (size_t)(brow * TC + tl) * 1024 + cz;
        A.Sh[so] = hi; A.Sl[so] = lo;
        if (A.t0 + tl == 511) A.hidout[(size_t)(brow * 2 + A.layer) * 1024 + cz] = hn;
      }
    }
    tgt += 64; gbar(cnt, gen, tgt);
  }
  if (w == 0) {
#pragma unroll
    for (int r = 0; r < 4; ++r)
      A.h32g[(grp * 16 + lkq * 4 + r) * 1024 + cz] = h32[r];
  }
}

// ---------- workspace layout (bytes); ~48 MiB ----------
static constexpr size_t OFF_WXT0H   = 0;                                  // [3072][512]
static constexpr size_t OFF_WXT0L   = OFF_WXT0H + 3072ull * 512 * 2;
static constexpr size_t OFF_WHZRT0H = OFF_WXT0L + 3072ull * 512 * 2;      // [2048][1024]
static constexpr size_t OFF_WHZRT0L = OFF_WHZRT0H + 2048ull * 1024 * 2;
static constexpr size_t OFF_WHGT0H  = OFF_WHZRT0L + 2048ull * 1024 * 2;   // [1024][1024]
static constexpr size_t OFF_WHGT0L  = OFF_WHGT0H + 1024ull * 1024 * 2;
static constexpr size_t OFF_WXT1H   = OFF_WHGT0L + 1024ull * 1024 * 2;    // [3072][1024]
static constexpr size_t OFF_WXT1L   = OFF_WXT1H + 3072ull * 1024 * 2;
static constexpr size_t OFF_WHZRT1H = OFF_WXT1L + 3072ull * 1024 * 2;
static constexpr size_t OFF_WHZRT1L = OFF_WHZRT1H + 2048ull * 1024 * 2;
static constexpr size_t OFF_WHGT1H  = OFF_WHZRT1L + 2048ull * 1024 * 2;
static constexpr size_t OFF_WHGT1L  = OFF_WHGT1H + 1024ull * 1024 * 2;
static constexpr size_t OFF_WHYTH   = OFF_WHGT1L + 1024ull * 1024 * 2;    // [512][1024]
static constexpr size_t OFF_WHYTL   = OFF_WHYTH + 512ull * 1024 * 2;
static constexpr size_t OFF_PC      = OFF_WHYTL + 512ull * 1024 * 2;      // [1024][3072] f32
static constexpr size_t OFF_S0H     = OFF_PC + 1024ull * 3072 * 4;        // [1024][1024] bf16
static constexpr size_t OFF_S0L     = OFF_S0H + 1024ull * 1024 * 2;
static constexpr size_t OFF_S1H     = OFF_S0L + 1024ull * 1024 * 2;       // also Xh alias
static constexpr size_t OFF_S1L     = OFF_S1H + 1024ull * 1024 * 2;       // also Xl alias
static constexpr size_t OFF_HBH0    = OFF_S1L + 1024ull * 1024 * 2;       // [64][1024] bf16
static constexpr size_t OFF_HBL0    = OFF_HBH0 + 64ull * 1024 * 2;
static constexpr size_t OFF_HBH1    = OFF_HBL0 + 64ull * 1024 * 2;
static constexpr size_t OFF_HBL1    = OFF_HBH1 + 64ull * 1024 * 2;
static constexpr size_t OFF_H320    = OFF_HBL1 + 64ull * 1024 * 2;        // [64][1024] f32
static constexpr size_t OFF_H321    = OFF_H320 + 64ull * 1024 * 4;
static constexpr size_t OFF_RHH     = OFF_H321 + 64ull * 1024 * 4;        // [64][1024] bf16
static constexpr size_t OFF_RHL     = OFF_RHH + 64ull * 1024 * 2;
static constexpr size_t OFF_BAR     = OFF_RHL + 64ull * 1024 * 2;         // 2 KB counters
static constexpr size_t OFF_END     = OFF_BAR + 2048;

extern "C" void kernel_launch(void* const* d_in, const int* in_sizes, int n_in,
                              void* d_out, int out_size, void* d_ws, size_t ws_size,
                              hipStream_t stream) {
  if (ws_size < OFF_END) return;  // clean fail: zeros => absmax 12.875 signature

  const float* x     = (const float*)d_in[0];
  const float* h0    = (const float*)d_in[1];
  const float* W_xz0 = (const float*)d_in[2];
  const float* W_hz0 = (const float*)d_in[3];
  const float* b_z0  = (const float*)d_in[4];
  const float* W_xr0 = (const float*)d_in[5];
  const float* W_hr0 = (const float*)d_in[6];
  const float* b_r0  = (const float*)d_in[7];
  const float* W_xg0 = (const float*)d_in[8];
  const float* W_hg0 = (const float*)d_in[9];
  const float* b_g0  = (const float*)d_in[10];
  const float* W_xz1 = (const float*)d_in[11];
  const float* W_hz1 = (const float*)d_in[12];
  const float* b_z1  = (const float*)d_in[13];
  const float* W_xr1 = (const float*)d_in[14];
  const float* W_hr1 = (const float*)d_in[15];
  const float* b_r1  = (const float*)d_in[16];
  const float* W_xg1 = (const float*)d_in[17];
  const float* W_hg1 = (const float*)d_in[18];
  const float* b_g1  = (const float*)d_in[19];
  const float* W_hy  = (const float*)d_in[20];
  const float* b_y   = (const float*)d_in[21];

  char* ws = (char*)d_ws;
  float* out_y   = (float*)d_out;                  // [64,512,512]
  float* out_hid = (float*)d_out + 16777216;       // [64,2,1024]
  unsigned* barc = (unsigned*)(ws + OFF_BAR);

  hipMemsetAsync(barc, 0, 2048, stream);

  // weight transpose + hi/lo split: dst[n][k] = src[k][n]
#define TRS(W, OFF_H, OFF_L, kbits, Nsrc, total) \
  tr_cvt_split<<<2048, 256, 0, stream>>>(W, (ushort*)(ws + OFF_H), (ushort*)(ws + OFF_L), kbits, Nsrc, total)
  TRS(W_xz0, OFF_WXT0H,                  OFF_WXT0L,                   9, 1024, 1024 * 512);
  TRS(W_xr0, OFF_WXT0H + 1024ull*512*2,  OFF_WXT0L + 1024ull*512*2,   9, 1024, 1024 * 512);
  TRS(W_xg0, OFF_WXT0H + 2048ull*512*2,  OFF_WXT0L + 2048ull*512*2,   9, 1024, 1024 * 512);
  TRS(W_hz0, OFF_WHZRT0H,                OFF_WHZRT0L,                10, 1024, 1024 * 1024);
  TRS(W_hr0, OFF_WHZRT0H + 1024ull*1024*2, OFF_WHZRT0L + 1024ull*1024*2, 10, 1024, 1024 * 1024);
  TRS(W_hg0, OFF_WHGT0H,                 OFF_WHGT0L,                 10, 1024, 1024 * 1024);
  TRS(W_xz1, OFF_WXT1H,                  OFF_WXT1L,                  10, 1024, 1024 * 1024);
  TRS(W_xr1, OFF_WXT1H + 1024ull*1024*2, OFF_WXT1L + 1024ull*1024*2, 10, 1024, 1024 * 1024);
  TRS(W_xg1, OFF_WXT1H + 2048ull*1024*2, OFF_WXT1L + 2048ull*1024*2, 10, 1024, 1024 * 1024);
  TRS(W_hz1, OFF_WHZRT1H,                OFF_WHZRT1L,                10, 1024, 1024 * 1024);
  TRS(W_hr1, OFF_WHZRT1H + 1024ull*1024*2, OFF_WHZRT1L + 1024ull*1024*2, 10, 1024, 1024 * 1024);
  TRS(W_hg1, OFF_WHGT1H,                 OFF_WHGT1L,                 10, 1024, 1024 * 1024);
  TRS(W_hy,  OFF_WHYTH,                  OFF_WHYTL,                  10, 512,  512 * 1024);
#undef TRS

  float*  Pc  = (float*)(ws + OFF_PC);
  ushort* S0h = (ushort*)(ws + OFF_S0H);
  ushort* S0l = (ushort*)(ws + OFF_S0L);
  ushort* S1h = (ushort*)(ws + OFF_S1H);
  ushort* S1l = (ushort*)(ws + OFF_S1L);
  ushort* Xh  = S1h;  // alias: X planes live split_x -> proj0; S1 live scan1 -> outproj
  ushort* Xl  = S1l;

  for (int c = 0; c < 512 / TC; ++c) {
    int t0 = c * TC;
    split_x_chunk<<<1024, 256, 0, stream>>>(x, Xh, Xl, t0);
    gemm3p<0><<<dim3(8, 24), 256, 0, stream>>>(
        Xh, Xl, (const ushort*)(ws + OFF_WXT0H), (const ushort*)(ws + OFF_WXT0L),
        Pc, nullptr, 1024, 3072, 512, 0);
    {
      ScanArgs sa;
      sa.P = Pc; sa.bz = b_z0; sa.br = b_r0; sa.bg = b_g0;
      sa.WhzrH = (const ushort*)(ws + OFF_WHZRT0H); sa.WhzrL = (const ushort*)(ws + OFF_WHZRT0L);
      sa.WhgH = (const ushort*)(ws + OFF_WHGT0H);   sa.WhgL = (const ushort*)(ws + OFF_WHGT0L);
      sa.h0 = h0; sa.layer = 0; sa.t0 = t0;
      sa.h32g = (float*)(ws + OFF_H320);
      sa.hbh = (ushort*)(ws + OFF_HBH0); sa.hbl = (ushort*)(ws + OFF_HBL0);
      sa.rhh = (ushort*)(ws + OFF_RHH);  sa.rhl = (ushort*)(ws + OFF_RHL);
      sa.Sh = S0h; sa.Sl = S0l; sa.hidout = out_hid;
      sa.barc = barc; sa.bar_base = (unsigned)((c * 2 + 0) * 33 * 64);
      gru_scan<<<256, 256, 0, stream>>>(sa);
    }
    gemm3p<0><<<dim3(8, 24), 256, 0, stream>>>(
        S0h, S0l, (const ushort*)(ws + OFF_WXT1H), (const ushort*)(ws + OFF_WXT1L),
        Pc, nullptr, 1024, 3072, 1024, 0);
    {
      ScanArgs sa;
      sa.P = Pc; sa.bz = b_z1; sa.br = b_r1; sa.bg = b_g1;
      sa.WhzrH = (const ushort*)(ws + OFF_WHZRT1H); sa.WhzrL = (const ushort*)(ws + OFF_WHZRT1L);
      sa.WhgH = (const ushort*)(ws + OFF_WHGT1H);   sa.WhgL = (const ushort*)(ws + OFF_WHGT1L);
      sa.h0 = h0; sa.layer = 1; sa.t0 = t0;
      sa.h32g = (float*)(ws + OFF_H321);
      sa.hbh = (ushort*)(ws + OFF_HBH1); sa.hbl = (ushort*)(ws + OFF_HBL1);
      sa.rhh = (ushort*)(ws + OFF_RHH);  sa.rhl = (ushort*)(ws + OFF_RHL);
      sa.Sh = S1h; sa.Sl = S1l; sa.hidout = out_hid;
      sa.barc = barc; sa.bar_base = (unsigned)((c * 2 + 1) * 33 * 64);
      gru_scan<<<256, 256, 0, stream>>>(sa);
    }
    gemm3p<1><<<dim3(8, 4), 256, 0, stream>>>(
        S1h, S1l, (const ushort*)(ws + OFF_WHYTH), (const ushort*)(ws + OFF_WHYTL),
        out_y, b_y, 1024, 512, 1024, t0);
  }
}

// Round 9
// 21918.802 us; speedup vs baseline: 5.1626x; 1.0521x over previous
//
#include <hip/hip_runtime.h>

typedef short s16x8 __attribute__((ext_vector_type(8)));
typedef unsigned short us8 __attribute__((ext_vector_type(8)));
typedef float f32x4 __attribute__((ext_vector_type(4)));

#define TC 16   // time-chunk length

// ---------- helpers ----------
__device__ __forceinline__ ushort f2bf(float f) {
  union { float f; unsigned u; } v; v.f = f;
  unsigned u = v.u;
  u += 0x7fffu + ((u >> 16) & 1u);
  return (ushort)(u >> 16);
}
__device__ __forceinline__ float bf2f(ushort h) {
  union { unsigned u; float f; } v; v.u = ((unsigned)h) << 16; return v.f;
}
__device__ __forceinline__ float sigm(float x) { return 1.f / (1.f + __expf(-x)); }
__device__ __forceinline__ float tanh_(float x) { return 1.f - 2.f / (__expf(2.f * x) + 1.f); }

#define MFMA __builtin_amdgcn_mfma_f32_16x16x32_bf16

// device-coherent 16B load (bypass L1/L2); batch + s_waitcnt vmcnt(0) before use
__device__ __forceinline__ s16x8 ld_sc16(const ushort* p) {
  s16x8 v;
  asm volatile("global_load_dwordx4 %0, %1, off sc0 sc1" : "=v"(v) : "v"(p));
  return v;
}
// device-coherent 2B store (write-through)
__device__ __forceinline__ void st_sc2(ushort* p, ushort x) {
  unsigned v = x;
  asm volatile("global_store_short %0, %1, off sc0 sc1" :: "v"(p), "v"(v) : "memory");
}

// ---------- transpose + split-convert: dst_{hi,lo}[n][k] = split(src[k][n]) ----------
__global__ void tr_cvt_split(const float* __restrict__ src, ushort* __restrict__ hi,
                             ushort* __restrict__ lo, int kbits, int Nsrc, int total) {
  int K1 = (1 << kbits) - 1;
  for (int i = blockIdx.x * blockDim.x + threadIdx.x; i < total; i += gridDim.x * blockDim.x) {
    int n = i >> kbits, k = i & K1;
    float v = src[(size_t)k * Nsrc + n];
    ushort h = f2bf(v);
    hi[i] = h;
    lo[i] = f2bf(v - bf2f(h));
  }
}

// ---------- split x chunk rows into hi/lo planes (chunk-row order) ----------
__global__ void split_x_chunk(const float* __restrict__ x, ushort* __restrict__ Xh,
                              ushort* __restrict__ Xl, int t0) {
  for (int i = blockIdx.x * blockDim.x + threadIdx.x; i < 1024 * 512;
       i += gridDim.x * blockDim.x) {
    int ar = i >> 9, k = i & 511;
    size_t grow = (size_t)(ar >> 4) * 512 + t0 + (ar & 15);
    float v = x[grow * 512 + k];
    ushort h = f2bf(v);
    Xh[i] = h;
    Xl[i] = f2bf(v - bf2f(h));
  }
}

// ---------- 3-term split GEMM from pre-split planes ----------
template <int C_MODE>
__global__ __launch_bounds__(256) void gemm3p(
    const ushort* __restrict__ Ah, const ushort* __restrict__ Al,
    const ushort* __restrict__ Bh, const ushort* __restrict__ Bl,
    float* __restrict__ Cout, const float* __restrict__ bias,
    int M, int N, int K, int t0) {
  __shared__ __align__(16) ushort Ahs[128][72];
  __shared__ __align__(16) ushort Als[128][72];
  __shared__ __align__(16) ushort Bhs[128][72];
  __shared__ __align__(16) ushort Bls[128][72];
  const int bm = blockIdx.x, bn = blockIdx.y;
  const int tid = threadIdx.x, lane = tid & 63;
  const int w = tid >> 6;
  const int wm = (w >> 1) * 64, wn = (w & 1) * 64;
  const int lr = lane & 15;
  const int lk = (lane >> 4) * 8;
  f32x4 acc[4][4] = {};
  for (int k0 = 0; k0 < K; k0 += 64) {
#pragma unroll
    for (int i = 0; i < 4; ++i) {
      int chunk = tid + i * 256;
      int row = chunk >> 3, c = (chunk & 7) * 8;
      size_t ao = (size_t)(bm * 128 + row) * K + k0 + c;
      size_t bo = (size_t)(bn * 128 + row) * K + k0 + c;
      *(int4*)(&Ahs[row][c]) = *(const int4*)(&Ah[ao]);
      *(int4*)(&Als[row][c]) = *(const int4*)(&Al[ao]);
      *(int4*)(&Bhs[row][c]) = *(const int4*)(&Bh[bo]);
      *(int4*)(&Bls[row][c]) = *(const int4*)(&Bl[bo]);
    }
    __syncthreads();
#pragma unroll
    for (int kk = 0; kk < 64; kk += 32) {
      s16x8 ah[4], al[4], bh[4], bl[4];
#pragma unroll
      for (int i = 0; i < 4; ++i) {
        ah[i] = *(const s16x8*)(&Ahs[wm + i * 16 + lr][kk + lk]);
        al[i] = *(const s16x8*)(&Als[wm + i * 16 + lr][kk + lk]);
      }
#pragma unroll
      for (int j = 0; j < 4; ++j) {
        bh[j] = *(const s16x8*)(&Bhs[wn + j * 16 + lr][kk + lk]);
        bl[j] = *(const s16x8*)(&Bls[wn + j * 16 + lr][kk + lk]);
      }
#pragma unroll
      for (int i = 0; i < 4; ++i)
#pragma unroll
        for (int j = 0; j < 4; ++j) {
          acc[i][j] = MFMA(ah[i], bh[j], acc[i][j], 0, 0, 0);
          acc[i][j] = MFMA(al[i], bh[j], acc[i][j], 0, 0, 0);
          acc[i][j] = MFMA(ah[i], bl[j], acc[i][j], 0, 0, 0);
        }
    }
    __syncthreads();
  }
#pragma unroll
  for (int i = 0; i < 4; ++i)
#pragma unroll
    for (int j = 0; j < 4; ++j)
#pragma unroll
      for (int r = 0; r < 4; ++r) {
        int lrow = bm * 128 + wm + i * 16 + (lane >> 4) * 4 + r;
        int gcol = bn * 128 + wn + j * 16 + lr;
        float v = acc[i][j][r];
        if (C_MODE == 1) {
          size_t grow = (size_t)(lrow >> 4) * 512 + t0 + (lrow & 15);
          Cout[grow * N + gcol] = v + bias[gcol];
        } else {
          Cout[(size_t)lrow * N + gcol] = v;
        }
      }
}

// ---------- flag-array group barrier: sc-store own flag, wave0 polls all 64 ----------
// No contended RMW, no gen round-trip. Monotonic tgt => no reset/reuse race.
// Comm data is write-through sc0sc1, drained by vmcnt(0)+syncthreads before arrival.
__device__ __forceinline__ void gbarf(unsigned* flags, int wgc, unsigned tgt) {
  asm volatile("s_waitcnt vmcnt(0)" ::: "memory");
  __syncthreads();
  if (threadIdx.x < 64) {
    if (threadIdx.x == 0) {
      unsigned* fp = flags + wgc;
      asm volatile("global_store_dword %0, %1, off sc0 sc1" :: "v"(fp), "v"(tgt) : "memory");
    }
    const unsigned* pp = flags + threadIdx.x;
    for (;;) {
      unsigned v;
      asm volatile("global_load_dword %0, %1, off sc0 sc1" : "=v"(v) : "v"(pp) : "memory");
      asm volatile("s_waitcnt vmcnt(0)" ::: "memory");
      if (__all(v >= tgt)) break;
      __builtin_amdgcn_s_sleep(1);
    }
  }
  __syncthreads();
}

// ---------- persistent GRU scan: 4 independent 16-row groups x 64 col-slice WGs ----------
// Grid 256 WGs x 256 thr (1 WG/CU). 4 waves K-split (256 each) + LDS reduce;
// wave w finalizes acc element w (row lkq*4+w) -> finalize 4x parallel.
// Wg hi/lo hoisted to registers (loop-invariant). Numerics identical to r8 PASS.
struct ScanArgs {
  const float* P;              // [64*TC][3072] f32 chunk (z|r|g)
  const float *bz, *br, *bg;
  const ushort *WhzrH, *WhzrL; // [2048][1024] bf16 hi/lo
  const ushort *WhgH, *WhgL;   // [1024][1024] bf16 hi/lo
  const float* h0;
  int layer, t0;
  float* h32g;                 // [64][1024] f32 carry
  ushort *hbh, *hbl;           // [64][1024] bf16 hi/lo of h   (sc comm)
  ushort *rhh, *rhl;           // [64][1024] bf16 hi/lo of r*h (sc comm)
  ushort *Sh, *Sl;             // [64*TC][1024] bf16 hi/lo seq output
  float* hidout;               // [64][2][1024] f32
  unsigned* flags;             // 4 groups x 64 flag words
  unsigned bar_base;           // launch_idx * 33
};

__global__ __launch_bounds__(256) void gru_scan(ScanArgs A) {
  __shared__ __align__(16) ushort Wzh[16][1032];
  __shared__ __align__(16) ushort Wzl[16][1032];
  __shared__ __align__(16) ushort Wrh[16][1032];
  __shared__ __align__(16) ushort Wrl[16][1032];
  __shared__ float red[4][64][9];
  const int tid = threadIdx.x, lane = tid & 63, w = tid >> 6;
  const int grp = blockIdx.x >> 6;
  const int wgc = blockIdx.x & 63;
  const int lr = lane & 15, lkq = lane >> 4;
  const int cz = wgc * 16 + lr;
  const int kbase = w * 256;
  unsigned tgt = A.bar_base;
  unsigned* flags = A.flags + grp * 64;

  // stage Wz/Wr hi+lo slices into LDS
  {
    const ushort* s0 = A.WhzrH + (size_t)(wgc * 16) * 1024;
    const ushort* s1 = A.WhzrL + (size_t)(wgc * 16) * 1024;
    const ushort* s2 = A.WhzrH + (size_t)(1024 + wgc * 16) * 1024;
    const ushort* s3 = A.WhzrL + (size_t)(1024 + wgc * 16) * 1024;
#pragma unroll
    for (int j = 0; j < 8; ++j) {
      int id = tid + j * 256;
      int row = id >> 7, ko = (id & 127) * 8;
      *(int4*)(&Wzh[row][ko]) = *(const int4*)(s0 + row * 1024 + ko);
      *(int4*)(&Wzl[row][ko]) = *(const int4*)(s1 + row * 1024 + ko);
      *(int4*)(&Wrh[row][ko]) = *(const int4*)(s2 + row * 1024 + ko);
      *(int4*)(&Wrl[row][ko]) = *(const int4*)(s3 + row * 1024 + ko);
    }
  }

  // hoist Wg hi/lo fragments into registers (loop-invariant)
  s16x8 gh8[8], gl8[8];
  {
    const ushort* wgh = A.WhgH + (size_t)(wgc * 16 + lr) * 1024 + kbase + lkq * 8;
    const ushort* wgl = A.WhgL + (size_t)(wgc * 16 + lr) * 1024 + kbase + lkq * 8;
#pragma unroll
    for (int e = 0; e < 8; ++e) {
      gh8[e] = *(const s16x8*)(wgh + e * 32);
      gl8[e] = *(const s16x8*)(wgl + e * 32);
    }
  }

  const float bzc = A.bz[cz], brc = A.br[cz], bgc = A.bg[cz];
  const int myrow = lkq * 4 + w;          // row in 16-tile this lane finalizes
  const int brow = grp * 16 + myrow;
  float h32, zv = 0.f;

  if (A.t0 == 0) {
    float v = A.h0[(size_t)(brow * 2 + A.layer) * 1024 + cz];
    h32 = v;
    ushort hi = f2bf(v);
    st_sc2(&A.hbh[brow * 1024 + cz], hi);
    st_sc2(&A.hbl[brow * 1024 + cz], f2bf(v - bf2f(hi)));
  } else {
    h32 = A.h32g[brow * 1024 + cz];
  }
  tgt += 1; gbarf(flags, wgc, tgt);   // LDS staging + h init visibility

  const ushort* hhp = A.hbh + (size_t)(grp * 16 + lr) * 1024 + kbase + lkq * 8;
  const ushort* hlp = A.hbl + (size_t)(grp * 16 + lr) * 1024 + kbase + lkq * 8;
  const ushort* rhp = A.rhh + (size_t)(grp * 16 + lr) * 1024 + kbase + lkq * 8;
  const ushort* rlp = A.rhl + (size_t)(grp * 16 + lr) * 1024 + kbase + lkq * 8;

  for (int tl = 0; tl < TC; ++tl) {
    const size_t prow = (size_t)(brow * TC + tl) * 3072;
    // ---- stage 1: partial z,r over this wave's K-quarter ----
    {
      float pz = A.P[prow + cz];
      float pr = A.P[prow + 1024 + cz];
      s16x8 hh[8], hl[8];
#pragma unroll
      for (int e = 0; e < 8; ++e) {
        hh[e] = ld_sc16(hhp + e * 32);
        hl[e] = ld_sc16(hlp + e * 32);
      }
      asm volatile("s_waitcnt vmcnt(0)" ::: "memory");
      __builtin_amdgcn_sched_barrier(0);
      f32x4 az = {}, ar4 = {};
#pragma unroll
      for (int ks = 0; ks < 8; ++ks) {
        int kc = kbase + ks * 32 + lkq * 8;
        s16x8 wz = *(const s16x8*)(&Wzh[lr][kc]);
        s16x8 wr = *(const s16x8*)(&Wrh[lr][kc]);
        s16x8 zl = *(const s16x8*)(&Wzl[lr][kc]);
        s16x8 rl = *(const s16x8*)(&Wrl[lr][kc]);
        az = MFMA(hh[ks], wz, az, 0, 0, 0);
        az = MFMA(hl[ks], wz, az, 0, 0, 0);
        az = MFMA(hh[ks], zl, az, 0, 0, 0);
        ar4 = MFMA(hh[ks], wr, ar4, 0, 0, 0);
        ar4 = MFMA(hl[ks], wr, ar4, 0, 0, 0);
        ar4 = MFMA(hh[ks], rl, ar4, 0, 0, 0);
      }
#pragma unroll
      for (int i = 0; i < 4; ++i) { red[w][lane][i] = az[i]; red[w][lane][4 + i] = ar4[i]; }
      __syncthreads();
      // per-lane finalize: row myrow, col cz
      float azs = red[0][lane][w] + red[1][lane][w] + red[2][lane][w] + red[3][lane][w];
      float ars = red[0][lane][4 + w] + red[1][lane][4 + w] +
                  red[2][lane][4 + w] + red[3][lane][4 + w];
      zv = sigm(pz + bzc + azs);
      float rv = sigm(pr + brc + ars);
      float p = rv * h32;
      ushort ph = f2bf(p);
      st_sc2(&A.rhh[brow * 1024 + cz], ph);
      st_sc2(&A.rhl[brow * 1024 + cz], f2bf(p - bf2f(ph)));
    }
    tgt += 1; gbarf(flags, wgc, tgt);
    // ---- stage 2: partial g over this wave's K-quarter ----
    {
      float pg = A.P[prow + 2048 + cz];
      s16x8 rh8[8], rl8[8];
#pragma unroll
      for (int e = 0; e < 8; ++e) {
        rh8[e] = ld_sc16(rhp + e * 32);
        rl8[e] = ld_sc16(rlp + e * 32);
      }
      asm volatile("s_waitcnt vmcnt(0)" ::: "memory");
      __builtin_amdgcn_sched_barrier(0);
      f32x4 ag = {};
#pragma unroll
      for (int ks = 0; ks < 8; ++ks) {
        ag = MFMA(rh8[ks], gh8[ks], ag, 0, 0, 0);
        ag = MFMA(rl8[ks], gh8[ks], ag, 0, 0, 0);
        ag = MFMA(rh8[ks], gl8[ks], ag, 0, 0, 0);
      }
#pragma unroll
      for (int i = 0; i < 4; ++i) red[w][lane][i] = ag[i];
      __syncthreads();
      float ags = red[0][lane][w] + red[1][lane][w] + red[2][lane][w] + red[3][lane][w];
      float g = tanh_(pg + bgc + ags);
      float hn = zv * h32 + (1.f - zv) * g;
      h32 = hn;
      ushort hi = f2bf(hn);
      ushort lo = f2bf(hn - bf2f(hi));
      st_sc2(&A.hbh[brow * 1024 + cz], hi);
      st_sc2(&A.hbl[brow * 1024 + cz], lo);
      size_t so = (size_t)(brow * TC + tl) * 1024 + cz;
      A.Sh[so] = hi; A.Sl[so] = lo;
      if (A.t0 + tl == 511) A.hidout[(size_t)(brow * 2 + A.layer) * 1024 + cz] = hn;
    }
    tgt += 1; gbarf(flags, wgc, tgt);
  }
  A.h32g[brow * 1024 + cz] = h32;
}

// ---------- workspace layout (bytes); ~48 MiB ----------
static constexpr size_t OFF_WXT0H   = 0;                                  // [3072][512]
static constexpr size_t OFF_WXT0L   = OFF_WXT0H + 3072ull * 512 * 2;
static constexpr size_t OFF_WHZRT0H = OFF_WXT0L + 3072ull * 512 * 2;      // [2048][1024]
static constexpr size_t OFF_WHZRT0L = OFF_WHZRT0H + 2048ull * 1024 * 2;
static constexpr size_t OFF_WHGT0H  = OFF_WHZRT0L + 2048ull * 1024 * 2;   // [1024][1024]
static constexpr size_t OFF_WHGT0L  = OFF_WHGT0H + 1024ull * 1024 * 2;
static constexpr size_t OFF_WXT1H   = OFF_WHGT0L + 1024ull * 1024 * 2;    // [3072][1024]
static constexpr size_t OFF_WXT1L   = OFF_WXT1H + 3072ull * 1024 * 2;
static constexpr size_t OFF_WHZRT1H = OFF_WXT1L + 3072ull * 1024 * 2;
static constexpr size_t OFF_WHZRT1L = OFF_WHZRT1H + 2048ull * 1024 * 2;
static constexpr size_t OFF_WHGT1H  = OFF_WHZRT1L + 2048ull * 1024 * 2;
static constexpr size_t OFF_WHGT1L  = OFF_WHGT1H + 1024ull * 1024 * 2;
static constexpr size_t OFF_WHYTH   = OFF_WHGT1L + 1024ull * 1024 * 2;    // [512][1024]
static constexpr size_t OFF_WHYTL   = OFF_WHYTH + 512ull * 1024 * 2;
static constexpr size_t OFF_PC      = OFF_WHYTL + 512ull * 1024 * 2;      // [1024][3072] f32
static constexpr size_t OFF_S0H     = OFF_PC + 1024ull * 3072 * 4;        // [1024][1024] bf16
static constexpr size_t OFF_S0L     = OFF_S0H + 1024ull * 1024 * 2;
static constexpr size_t OFF_S1H     = OFF_S0L + 1024ull * 1024 * 2;       // also Xh alias
static constexpr size_t OFF_S1L     = OFF_S1H + 1024ull * 1024 * 2;       // also Xl alias
static constexpr size_t OFF_HBH0    = OFF_S1L + 1024ull * 1024 * 2;       // [64][1024] bf16
static constexpr size_t OFF_HBL0    = OFF_HBH0 + 64ull * 1024 * 2;
static constexpr size_t OFF_HBH1    = OFF_HBL0 + 64ull * 1024 * 2;
static constexpr size_t OFF_HBL1    = OFF_HBH1 + 64ull * 1024 * 2;
static constexpr size_t OFF_H320    = OFF_HBL1 + 64ull * 1024 * 2;        // [64][1024] f32
static constexpr size_t OFF_H321    = OFF_H320 + 64ull * 1024 * 4;
static constexpr size_t OFF_RHH     = OFF_H321 + 64ull * 1024 * 4;        // [64][1024] bf16
static constexpr size_t OFF_RHL     = OFF_RHH + 64ull * 1024 * 2;
static constexpr size_t OFF_BAR     = OFF_RHL + 64ull * 1024 * 2;         // 2 KB flags
static constexpr size_t OFF_END     = OFF_BAR + 2048;

extern "C" void kernel_launch(void* const* d_in, const int* in_sizes, int n_in,
                              void* d_out, int out_size, void* d_ws, size_t ws_size,
                              hipStream_t stream) {
  if (ws_size < OFF_END) return;  // clean fail: zeros => absmax 12.875 signature

  const float* x     = (const float*)d_in[0];
  const float* h0    = (const float*)d_in[1];
  const float* W_xz0 = (const float*)d_in[2];
  const float* W_hz0 = (const float*)d_in[3];
  const float* b_z0  = (const float*)d_in[4];
  const float* W_xr0 = (const float*)d_in[5];
  const float* W_hr0 = (const float*)d_in[6];
  const float* b_r0  = (const float*)d_in[7];
  const float* W_xg0 = (const float*)d_in[8];
  const float* W_hg0 = (const float*)d_in[9];
  const float* b_g0  = (const float*)d_in[10];
  const float* W_xz1 = (const float*)d_in[11];
  const float* W_hz1 = (const float*)d_in[12];
  const float* b_z1  = (const float*)d_in[13];
  const float* W_xr1 = (const float*)d_in[14];
  const float* W_hr1 = (const float*)d_in[15];
  const float* b_r1  = (const float*)d_in[16];
  const float* W_xg1 = (const float*)d_in[17];
  const float* W_hg1 = (const float*)d_in[18];
  const float* b_g1  = (const float*)d_in[19];
  const float* W_hy  = (const float*)d_in[20];
  const float* b_y   = (const float*)d_in[21];

  char* ws = (char*)d_ws;
  float* out_y   = (float*)d_out;                  // [64,512,512]
  float* out_hid = (float*)d_out + 16777216;       // [64,2,1024]
  unsigned* flags = (unsigned*)(ws + OFF_BAR);

  hipMemsetAsync(flags, 0, 2048, stream);

  // weight transpose + hi/lo split: dst[n][k] = src[k][n]
#define TRS(W, OFF_H, OFF_L, kbits, Nsrc, total) \
  tr_cvt_split<<<2048, 256, 0, stream>>>(W, (ushort*)(ws + OFF_H), (ushort*)(ws + OFF_L), kbits, Nsrc, total)
  TRS(W_xz0, OFF_WXT0H,                  OFF_WXT0L,                   9, 1024, 1024 * 512);
  TRS(W_xr0, OFF_WXT0H + 1024ull*512*2,  OFF_WXT0L + 1024ull*512*2,   9, 1024, 1024 * 512);
  TRS(W_xg0, OFF_WXT0H + 2048ull*512*2,  OFF_WXT0L + 2048ull*512*2,   9, 1024, 1024 * 512);
  TRS(W_hz0, OFF_WHZRT0H,                OFF_WHZRT0L,                10, 1024, 1024 * 1024);
  TRS(W_hr0, OFF_WHZRT0H + 1024ull*1024*2, OFF_WHZRT0L + 1024ull*1024*2, 10, 1024, 1024 * 1024);
  TRS(W_hg0, OFF_WHGT0H,                 OFF_WHGT0L,                 10, 1024, 1024 * 1024);
  TRS(W_xz1, OFF_WXT1H,                  OFF_WXT1L,                  10, 1024, 1024 * 1024);
  TRS(W_xr1, OFF_WXT1H + 1024ull*1024*2, OFF_WXT1L + 1024ull*1024*2, 10, 1024, 1024 * 1024);
  TRS(W_xg1, OFF_WXT1H + 2048ull*1024*2, OFF_WXT1L + 2048ull*1024*2, 10, 1024, 1024 * 1024);
  TRS(W_hz1, OFF_WHZRT1H,                OFF_WHZRT1L,                10, 1024, 1024 * 1024);
  TRS(W_hr1, OFF_WHZRT1H + 1024ull*1024*2, OFF_WHZRT1L + 1024ull*1024*2, 10, 1024, 1024 * 1024);
  TRS(W_hg1, OFF_WHGT1H,                 OFF_WHGT1L,                 10, 1024, 1024 * 1024);
  TRS(W_hy,  OFF_WHYTH,                  OFF_WHYTL,                  10, 512,  512 * 1024);
#undef TRS

  float*  Pc  = (float*)(ws + OFF_PC);
  ushort* S0h = (ushort*)(ws + OFF_S0H);
  ushort* S0l = (ushort*)(ws + OFF_S0L);
  ushort* S1h = (ushort*)(ws + OFF_S1H);
  ushort* S1l = (ushort*)(ws + OFF_S1L);
  ushort* Xh  = S1h;  // alias: X planes live split_x -> proj0; S1 live scan1 -> outproj
  ushort* Xl  = S1l;

  for (int c = 0; c < 512 / TC; ++c) {
    int t0 = c * TC;
    split_x_chunk<<<1024, 256, 0, stream>>>(x, Xh, Xl, t0);
    gemm3p<0><<<dim3(8, 24), 256, 0, stream>>>(
        Xh, Xl, (const ushort*)(ws + OFF_WXT0H), (const ushort*)(ws + OFF_WXT0L),
        Pc, nullptr, 1024, 3072, 512, 0);
    {
      ScanArgs sa;
      sa.P = Pc; sa.bz = b_z0; sa.br = b_r0; sa.bg = b_g0;
      sa.WhzrH = (const ushort*)(ws + OFF_WHZRT0H); sa.WhzrL = (const ushort*)(ws + OFF_WHZRT0L);
      sa.WhgH = (const ushort*)(ws + OFF_WHGT0H);   sa.WhgL = (const ushort*)(ws + OFF_WHGT0L);
      sa.h0 = h0; sa.layer = 0; sa.t0 = t0;
      sa.h32g = (float*)(ws + OFF_H320);
      sa.hbh = (ushort*)(ws + OFF_HBH0); sa.hbl = (ushort*)(ws + OFF_HBL0);
      sa.rhh = (ushort*)(ws + OFF_RHH);  sa.rhl = (ushort*)(ws + OFF_RHL);
      sa.Sh = S0h; sa.Sl = S0l; sa.hidout = out_hid;
      sa.flags = flags; sa.bar_base = (unsigned)((c * 2 + 0) * 33);
      gru_scan<<<256, 256, 0, stream>>>(sa);
    }
    gemm3p<0><<<dim3(8, 24), 256, 0, stream>>>(
        S0h, S0l, (const ushort*)(ws + OFF_WXT1H), (const ushort*)(ws + OFF_WXT1L),
        Pc, nullptr, 1024, 3072, 1024, 0);
    {
      ScanArgs sa;
      sa.P = Pc; sa.bz = b_z1; sa.br = b_r1; sa.bg = b_g1;
      sa.WhzrH = (const ushort*)(ws + OFF_WHZRT1H); sa.WhzrL = (const ushort*)(ws + OFF_WHZRT1L);
      sa.WhgH = (const ushort*)(ws + OFF_WHGT1H);   sa.WhgL = (const ushort*)(ws + OFF_WHGT1L);
      sa.h0 = h0; sa.layer = 1; sa.t0 = t0;
      sa.h32g = (float*)(ws + OFF_H321);
      sa.hbh = (ushort*)(ws + OFF_HBH1); sa.hbl = (ushort*)(ws + OFF_HBL1);
      sa.rhh = (ushort*)(ws + OFF_RHH);  sa.rhl = (ushort*)(ws + OFF_RHL);
      sa.Sh = S1h; sa.Sl = S1l; sa.hidout = out_hid;
      sa.flags = flags; sa.bar_base = (unsigned)((c * 2 + 1) * 33);
      gru_scan<<<256, 256, 0, stream>>>(sa);
    }
    gemm3p<1><<<dim3(8, 4), 256, 0, stream>>>(
        S1h, S1l, (const ushort*)(ws + OFF_WHYTH), (const ushort*)(ws + OFF_WHYTL),
        out_y, b_y, 1024, 512, 1024, t0);
  }
}